// Round 1
// baseline (425.790 us; speedup 1.0000x reference)
//
#include <hip/hip_runtime.h>

#define BLK 256
#define E 2            // elements per thread
#define JSTR 104       // floats per j-block in LDS (16B-aligned stride)
#define LDSN (20*JSTR + 8)

// LDS layout per j (offsets in floats):
//   0..15  : W_ih rows {i,f,g,o} x 4 cols
//  16..19  : fused bias (b_ih+b_hh) for {i,f,g,o}
//  20      : W_theta_w[j]
//  21      : W_grad_w[j]
//  22..23  : pad
//  24..43  : W_hh row (i-gate, j)   [20]
//  44..63  : W_hh row (f-gate)
//  64..83  : W_hh row (g-gate)
//  84..103 : W_hh row (o-gate)
// tail at 20*JSTR: [Wtw[20], Wtw[21], Wtb, Wgw[20], Wgw[21], Wgb, 0, 0]

__device__ __forceinline__ float ex2(float x){ return __builtin_amdgcn_exp2f(x); }
__device__ __forceinline__ float rcp_(float x){ return __builtin_amdgcn_rcpf(x); }
__device__ __forceinline__ float lg2(float x){ return __builtin_amdgcn_logf(x); }

#define LOG2E 1.4426950408889634f

__device__ __forceinline__ float sigm(float x){
    return rcp_(1.0f + ex2(-LOG2E * x));
}
__device__ __forceinline__ float tanh_(float x){
    // tanh(x) = 1 - 2/(exp(2x)+1); saturates correctly for large |x|
    return 1.0f - 2.0f * rcp_(1.0f + ex2(2.8853900817779268f * x));
}

__global__ __launch_bounds__(BLK) void lstm_opt_kernel(
    const float* __restrict__ grad, const float* __restrict__ loss,
    const float* __restrict__ f1,   const float* __restrict__ i1,
    const float* __restrict__ th1,  const float* __restrict__ dl1,
    const float* __restrict__ h0,   const float* __restrict__ c0,
    const float* __restrict__ Wih,  const float* __restrict__ Whh,
    const float* __restrict__ bih,  const float* __restrict__ bhh,
    const float* __restrict__ Wtw,  const float* __restrict__ Wtb,
    const float* __restrict__ Wgw,  const float* __restrict__ Wgb,
    float* __restrict__ out)
{
    __shared__ __align__(16) float lds[LDSN];
    const int tid = threadIdx.x;

    // ---- stage packed weights into LDS ----
    for (int idx = tid; idx < 20*JSTR; idx += BLK) {
        const int j = idx / JSTR;
        const int r = idx - j*JSTR;
        float v;
        if (r < 16) {
            const int gate = r >> 2, col = r & 3;
            v = Wih[(gate*20 + j)*4 + col];
        } else if (r < 20) {
            const int gate = r - 16;
            v = bih[gate*20 + j] + bhh[gate*20 + j];
        } else if (r == 20) v = Wtw[j];
        else if (r == 21) v = Wgw[j];
        else if (r < 24) v = 0.0f;
        else {
            const int q = r - 24;
            const int gate = q / 20;
            const int k = q - gate*20;
            v = Whh[(gate*20 + j)*20 + k];
        }
        lds[idx] = v;
    }
    if (tid < 8) {
        float v = 0.0f;
        if      (tid == 0) v = Wtw[20];
        else if (tid == 1) v = Wtw[21];
        else if (tid == 2) v = Wtb[0];
        else if (tid == 3) v = Wgw[20];
        else if (tid == 4) v = Wgw[21];
        else if (tid == 5) v = Wgb[0];
        lds[20*JSTR + tid] = v;
    }
    __syncthreads();

    // ---- per-thread elements: base + e*BLK (coalesced across lanes) ----
    const int base = blockIdx.x * (BLK*E) + tid;

    float g_[E], x0[E], x1[E], x2[E], x3[E];
    const float* c0p[E];
    float h[E][20];

    #pragma unroll
    for (int e = 0; e < E; ++e) {
        const int n = base + e*BLK;
        const float g  = grad[n];
        const float lv = loss[n];
        g_[e] = g;
        const float ax = fabsf(g);
        const bool cg = ax >= 4.5399929762484854e-05f;     // exp(-10)
        x0[e] = cg ? lg2(ax) * 0.06931471805599453f : -1.0f; // ln(ax)/10
        x1[e] = cg ? copysignf(1.0f, g) : g * 22026.465794806718f; // exp(10)
        const float al = fabsf(lv);
        const bool cl = al >= 4.5399929762484854e-05f;
        x2[e] = cl ? lg2(al) * 0.06931471805599453f : -1.0f;
        x3[e] = cl ? copysignf(1.0f, lv) : lv * 22026.465794806718f;

        c0p[e] = c0 + (size_t)n * 20;
        const float4* hp = (const float4*)(h0 + (size_t)n * 20);
        #pragma unroll
        for (int kb = 0; kb < 5; ++kb) {
            const float4 hv = hp[kb];
            h[e][kb*4+0] = hv.x; h[e][kb*4+1] = hv.y;
            h[e][kb*4+2] = hv.z; h[e][kb*4+3] = hv.w;
        }
    }

    float fac[E], iac[E];
    {
        const float tb = lds[20*JSTR + 2];
        const float gb = lds[20*JSTR + 5];
        #pragma unroll
        for (int e = 0; e < E; ++e) { fac[e] = tb; iac[e] = gb; }
    }

    // ---- 20 hidden units; rolled loop (I-cache), inner fully unrolled ----
    #pragma unroll 1
    for (int j = 0; j < 20; ++j) {
        const float* Lp = &lds[j * JSTR];

        float cv[E];
        #pragma unroll
        for (int e = 0; e < E; ++e) cv[e] = c0p[e][j];

        const float4 wii = *(const float4*)(Lp + 0);
        const float4 wif = *(const float4*)(Lp + 4);
        const float4 wig = *(const float4*)(Lp + 8);
        const float4 wio = *(const float4*)(Lp + 12);
        const float4 b4  = *(const float4*)(Lp + 16);
        const float wtw = Lp[20], wgw = Lp[21];

        float gi[E], gf[E], gg[E], go[E];
        #pragma unroll
        for (int e = 0; e < E; ++e) {
            gi[e] = b4.x + x0[e]*wii.x + x1[e]*wii.y + x2[e]*wii.z + x3[e]*wii.w;
            gf[e] = b4.y + x0[e]*wif.x + x1[e]*wif.y + x2[e]*wif.z + x3[e]*wif.w;
            gg[e] = b4.z + x0[e]*wig.x + x1[e]*wig.y + x2[e]*wig.z + x3[e]*wig.w;
            go[e] = b4.w + x0[e]*wio.x + x1[e]*wio.y + x2[e]*wio.z + x3[e]*wio.w;
        }

        #pragma unroll
        for (int kb = 0; kb < 5; ++kb) {
            const float4 whi = *(const float4*)(Lp + 24 + kb*4);
            const float4 whf = *(const float4*)(Lp + 44 + kb*4);
            const float4 whg = *(const float4*)(Lp + 64 + kb*4);
            const float4 who = *(const float4*)(Lp + 84 + kb*4);
            #pragma unroll
            for (int e = 0; e < E; ++e) {
                const float a0 = h[e][kb*4+0], a1 = h[e][kb*4+1];
                const float a2 = h[e][kb*4+2], a3 = h[e][kb*4+3];
                gi[e] += a0*whi.x + a1*whi.y + a2*whi.z + a3*whi.w;
                gf[e] += a0*whf.x + a1*whf.y + a2*whf.z + a3*whf.w;
                gg[e] += a0*whg.x + a1*whg.y + a2*whg.z + a3*whg.w;
                go[e] += a0*who.x + a1*who.y + a2*who.z + a3*who.w;
            }
        }

        #pragma unroll
        for (int e = 0; e < E; ++e) {
            const float ig = sigm(gi[e]);
            const float fg = sigm(gf[e]);
            const float gv = tanh_(gg[e]);
            const float og = sigm(go[e]);
            const float ct = fg*cv[e] + ig*gv;
            const float ht = og * tanh_(ct);
            fac[e] += ht * wtw;
            iac[e] += ht * wgw;
        }
    }

    // ---- heads + gated update ----
    const float wt20 = lds[20*JSTR+0], wt21 = lds[20*JSTR+1];
    const float wg20 = lds[20*JSTR+3], wg21 = lds[20*JSTR+4];
    #pragma unroll
    for (int e = 0; e < E; ++e) {
        const int n = base + e*BLK;
        const float th = th1[n];
        const float ff = f1[n];
        const float ii = i1[n];
        const float dl = dl1[n];
        const float ft = sigm(fac[e] + th*wt20 + ff*wt21);
        const float it = sigm(iac[e] + th*wg20 + ii*wg21);
        out[n] = ft*th + 0.1f*dl - it*g_[e];
    }
}

extern "C" void kernel_launch(void* const* d_in, const int* in_sizes, int n_in,
                              void* d_out, int out_size, void* d_ws, size_t ws_size,
                              hipStream_t stream) {
    const float* grad = (const float*)d_in[0];
    const float* loss = (const float*)d_in[1];
    const float* f1   = (const float*)d_in[2];
    const float* i1   = (const float*)d_in[3];
    const float* th1  = (const float*)d_in[4];
    const float* dl1  = (const float*)d_in[5];
    const float* h0   = (const float*)d_in[6];
    const float* c0   = (const float*)d_in[7];
    const float* Wih  = (const float*)d_in[8];
    const float* Whh  = (const float*)d_in[9];
    const float* bih  = (const float*)d_in[10];
    const float* bhh  = (const float*)d_in[11];
    const float* Wtw  = (const float*)d_in[12];
    const float* Wtb  = (const float*)d_in[13];
    const float* Wgw  = (const float*)d_in[14];
    const float* Wgb  = (const float*)d_in[15];

    const int N = in_sizes[0];            // 4194304, divisible by BLK*E
    const int blocks = N / (BLK * E);
    hipLaunchKernelGGL(lstm_opt_kernel, dim3(blocks), dim3(BLK), 0, stream,
                       grad, loss, f1, i1, th1, dl1, h0, c0,
                       Wih, Whh, bih, bhh, Wtw, Wtb, Wgw, Wgb,
                       (float*)d_out);
}

// Round 2
// 220.788 us; speedup vs baseline: 1.9285x; 1.9285x over previous
//
#include <hip/hip_runtime.h>

#define NP 16                 // 16-element passes per wave
#define WAVES 4
#define BLK (WAVES*64)

typedef __bf16 bf16x8 __attribute__((ext_vector_type(8)));
typedef float  f32x4  __attribute__((ext_vector_type(4)));

__device__ __forceinline__ float ex2(float x){ return __builtin_amdgcn_exp2f(x); }
__device__ __forceinline__ float rcp_(float x){ return __builtin_amdgcn_rcpf(x); }
__device__ __forceinline__ float lg2(float x){ return __builtin_amdgcn_logf(x); }
#define LOG2E 1.4426950408889634f

__device__ __forceinline__ float sigm(float x){ return rcp_(1.0f + ex2(-LOG2E*x)); }
__device__ __forceinline__ float tanh_(float x){ return 1.0f - 2.0f*rcp_(1.0f + ex2(2.8853900817779268f*x)); }

__device__ __forceinline__ unsigned cvtpk(float lo, float hi){
  unsigned r; asm("v_cvt_pk_bf16_f32 %0, %1, %2" : "=v"(r) : "v"(lo), "v"(hi)); return r;
}

__global__ __launch_bounds__(BLK) void lstm_opt_mfma(
    const float* __restrict__ grad, const float* __restrict__ loss,
    const float* __restrict__ f1,   const float* __restrict__ i1,
    const float* __restrict__ th1,  const float* __restrict__ dl1,
    const float* __restrict__ h0,   const float* __restrict__ c0,
    const float* __restrict__ Wih,  const float* __restrict__ Whh,
    const float* __restrict__ bih,  const float* __restrict__ bhh,
    const float* __restrict__ Wtw,  const float* __restrict__ Wtb,
    const float* __restrict__ Wgw,  const float* __restrict__ Wgb,
    float* __restrict__ out)
{
    const int tid  = threadIdx.x;
    const int lane = tid & 63;
    const int wid  = tid >> 6;
    const int e16  = lane & 15;   // elem-within-pass (B col / C col); also A row sel
    const int grp  = lane >> 4;   // k-chunk group / C row group

    // ---- prologue: per-lane weight A-fragments, biases (C-init), head weights ----
    // Gate-row ordering: g = j*4 + gate  (gate: 0=i,1=f,2=g,3=o)
    // Feature ordering:  k=0..19 -> h0..h19, k=20..23 -> x0..x3, k>=24 -> 0
    bf16x8 af[5];
    f32x4  bias4[5];
    float  wtwv[5], wgwv[5];
    int    jt[5];
    #pragma unroll
    for (int t = 0; t < 5; ++t) {
        const int gRow = t*16 + e16;
        const int j = gRow >> 2, gate = gRow & 3;
        const int r = gate*20 + j;                 // storage row in W_ih/W_hh
        float wf[8];
        #pragma unroll
        for (int i = 0; i < 8; ++i) {
            const int k = grp*8 + i;
            float v = 0.0f;
            if (k < 20)      v = Whh[r*20 + k];
            else if (k < 24) v = Wih[r*4 + (k - 20)];
            wf[i] = v;
        }
        union { unsigned u[4]; bf16x8 v; } pk;
        pk.u[0] = cvtpk(wf[0], wf[1]); pk.u[1] = cvtpk(wf[2], wf[3]);
        pk.u[2] = cvtpk(wf[4], wf[5]); pk.u[3] = cvtpk(wf[6], wf[7]);
        af[t] = pk.v;

        const int jj = 4*t + grp;                  // this lane's j for tile t
        jt[t] = jj;
        f32x4 b;
        #pragma unroll
        for (int m = 0; m < 4; ++m) b[m] = bih[m*20 + jj] + bhh[m*20 + jj];
        bias4[t] = b;
        wtwv[t] = Wtw[jj];
        wgwv[t] = Wgw[jj];
    }
    const float wt20 = Wtw[20], wt21 = Wtw[21], tb = Wtb[0];
    const float wg20 = Wgw[20], wg21 = Wgw[21], gb = Wgb[0];

    const int waveBase = (blockIdx.x * WAVES + wid) * (16 * NP);

    #pragma unroll 1
    for (int p = 0; p < NP; ++p) {
        const int e = waveBase + p*16 + e16;

        const float g  = grad[e];
        const float lv = loss[e];
        const float th = th1[e];
        const float ff = f1[e];
        const float ii = i1[e];
        const float dl = dl1[e];

        // preprocess -> x0..x3 (fp32)
        const float ax = fabsf(g);
        const bool  cg = ax >= 4.5399929762484854e-05f;          // exp(-10)
        const float x0 = cg ? lg2(ax) * 0.06931471805599453f : -1.0f;
        const float x1 = cg ? copysignf(1.0f, g) : g * 22026.465794806718f;
        const float al = fabsf(lv);
        const bool  cl = al >= 4.5399929762484854e-05f;
        const float x2 = cl ? lg2(al) * 0.06931471805599453f : -1.0f;
        const float x3 = cl ? copysignf(1.0f, lv) : lv * 22026.465794806718f;

        // B-fragment: this lane supplies features k = grp*8 .. grp*8+7 of elem e
        const float* hp = h0 + (size_t)e * 20;
        const int o0 = (grp == 0) ? 0 : (grp == 1) ? 8  : 16;    // grp3: dummy
        const int o1 = (grp == 0) ? 4 : (grp == 1) ? 12 : 16;    // grp2/3: dummy
        const float4 A4 = *(const float4*)(hp + o0);
        const float4 B4 = *(const float4*)(hp + o1);

        const bool z = (grp == 3);
        const float fa0 = z ? 0.0f : A4.x, fa1 = z ? 0.0f : A4.y;
        const float fa2 = z ? 0.0f : A4.z, fa3 = z ? 0.0f : A4.w;
        float fb0, fb1, fb2, fb3;
        if (grp == 2)      { fb0 = x0;  fb1 = x1;  fb2 = x2;  fb3 = x3;  }
        else if (z)        { fb0 = 0.f; fb1 = 0.f; fb2 = 0.f; fb3 = 0.f; }
        else               { fb0 = B4.x; fb1 = B4.y; fb2 = B4.z; fb3 = B4.w; }

        union { unsigned u[4]; bf16x8 v; } bp;
        bp.u[0] = cvtpk(fa0, fa1); bp.u[1] = cvtpk(fa2, fa3);
        bp.u[2] = cvtpk(fb0, fb1); bp.u[3] = cvtpk(fb2, fb3);
        const bf16x8 bfrag = bp.v;

        // gates^T[80,16] = W @ features^T, bias as C-in
        f32x4 acc[5];
        #pragma unroll
        for (int t = 0; t < 5; ++t) acc[t] = bias4[t];
        #pragma unroll
        for (int t = 0; t < 5; ++t)
            acc[t] = __builtin_amdgcn_mfma_f32_16x16x32_bf16(af[t], bfrag, acc[t], 0, 0, 0);

        // LSTM cell + head partials: lane owns (elem e16, j = 4t+grp), regs = i,f,g,o
        float fac = 0.0f, iac = 0.0f;
        const float* cp = c0 + (size_t)e * 20;
        #pragma unroll
        for (int t = 0; t < 5; ++t) {
            const float c0v = cp[jt[t]];
            const float si = sigm(acc[t][0]);
            const float sf = sigm(acc[t][1]);
            const float tg = tanh_(acc[t][2]);
            const float so = sigm(acc[t][3]);
            const float ct = sf * c0v + si * tg;
            const float ht = so * tanh_(ct);
            fac += ht * wtwv[t];
            iac += ht * wgwv[t];
        }
        // reduce the j-partials across the 4 lane groups
        fac += __shfl_xor(fac, 16); fac += __shfl_xor(fac, 32);
        iac += __shfl_xor(iac, 16); iac += __shfl_xor(iac, 32);

        if (grp == 0) {
            const float ft = sigm(fac + tb + th*wt20 + ff*wt21);
            const float it = sigm(iac + gb + th*wg20 + ii*wg21);
            out[e] = ft*th + 0.1f*dl - it*g;
        }
    }
}

extern "C" void kernel_launch(void* const* d_in, const int* in_sizes, int n_in,
                              void* d_out, int out_size, void* d_ws, size_t ws_size,
                              hipStream_t stream) {
    const float* grad = (const float*)d_in[0];
    const float* loss = (const float*)d_in[1];
    const float* f1   = (const float*)d_in[2];
    const float* i1   = (const float*)d_in[3];
    const float* th1  = (const float*)d_in[4];
    const float* dl1  = (const float*)d_in[5];
    const float* h0   = (const float*)d_in[6];
    const float* c0   = (const float*)d_in[7];
    const float* Wih  = (const float*)d_in[8];
    const float* Whh  = (const float*)d_in[9];
    const float* bih  = (const float*)d_in[10];
    const float* bhh  = (const float*)d_in[11];
    const float* Wtw  = (const float*)d_in[12];
    const float* Wtb  = (const float*)d_in[13];
    const float* Wgw  = (const float*)d_in[14];
    const float* Wgb  = (const float*)d_in[15];

    const int N = in_sizes[0];                 // 4194304 = 4096 * 1024
    const int blocks = N / (16 * NP * WAVES);
    hipLaunchKernelGGL(lstm_opt_mfma, dim3(blocks), dim3(BLK), 0, stream,
                       grad, loss, f1, i1, th1, dl1, h0, c0,
                       Wih, Whh, bih, bhh, Wtw, Wtb, Wgw, Wgb,
                       (float*)d_out);
}

// Round 3
// 191.762 us; speedup vs baseline: 2.2204x; 1.1514x over previous
//
#include <hip/hip_runtime.h>

#define NP 16
#define WAVES 4
#define BLK (WAVES*64)

typedef __bf16 bf16x8 __attribute__((ext_vector_type(8)));
typedef float  f32x4  __attribute__((ext_vector_type(4)));

__device__ __forceinline__ float ex2(float x){ return __builtin_amdgcn_exp2f(x); }
__device__ __forceinline__ float rcp_(float x){ return __builtin_amdgcn_rcpf(x); }
__device__ __forceinline__ float lg2(float x){ return __builtin_amdgcn_logf(x); }

#define LOG2E      1.4426950408889634f
#define TWOLOG2E   2.8853900817779268f
#define LN2_OVER_P 0.06931471805599453f     // ln2/10, folded into x0/x2 weight cols
#define NEG_PL2E  -14.426950408889634f      // -P/ln2 : u0 value when |x| < eps
#define EPSP       4.5399929762484854e-05f  // exp(-10)
#define EXPP       22026.465794806718f      // exp(10)

struct InSet { float g, lv; float4 hA, hB; float c5[5]; };

__device__ __forceinline__ void load_set(const float* __restrict__ grad,
                                         const float* __restrict__ loss,
                                         const float* __restrict__ h0,
                                         const float* __restrict__ c0,
                                         int e, int o0, int o1, int cOff, InSet& S)
{
    S.g  = grad[e];
    S.lv = loss[e];
    const float* hp = h0 + (size_t)e * 20;
    S.hA = *(const float4*)(hp + o0);
    S.hB = *(const float4*)(hp + o1);
    const float* cp = c0 + (size_t)e * 20 + cOff;
    #pragma unroll
    for (int i = 0; i < 5; ++i) S.c5[i] = cp[i];
}

__global__ __launch_bounds__(BLK, 4) void lstm_opt_mfma(
    const float* __restrict__ grad, const float* __restrict__ loss,
    const float* __restrict__ f1,   const float* __restrict__ i1,
    const float* __restrict__ th1,  const float* __restrict__ dl1,
    const float* __restrict__ h0,   const float* __restrict__ c0,
    const float* __restrict__ Wih,  const float* __restrict__ Whh,
    const float* __restrict__ bih,  const float* __restrict__ bhh,
    const float* __restrict__ Wtw,  const float* __restrict__ Wtb,
    const float* __restrict__ Wgw,  const float* __restrict__ Wgb,
    float* __restrict__ out)
{
    const int tid  = threadIdx.x;
    const int lane = tid & 63;
    const int wid  = tid >> 6;
    const int e16  = lane & 15;   // elem column / A row
    const int grp  = lane >> 4;   // k-chunk group / C row group

    // ---- prologue: per-lane prescaled weight A-fragments, biases, head weights ----
    // Row ordering: tile t, in-tile row r16 -> (gate = r16&3, j = 5*(r16>>2) + t)
    // C/D side: lane (e16, grp), reg m  ->  (gate = m, j = 5*grp + t)   [sigma remap]
    // Feature k: 0..19 = h0[k]; 20..23 = u0,x1,u2,x3; 24..31 = 0
    // Prescale: gates i,f,o by -LOG2E; gate g by +2*LOG2E; cols 20,22 by ln2/P.
    bf16x8 af[5];
    f32x4  bias4[5];
    float  wtwv[5], wgwv[5];
    {
        const int gate = e16 & 3;
        const int jA0  = 5 * (e16 >> 2);
        const float sg = (gate == 2) ? TWOLOG2E : -LOG2E;
        #pragma unroll
        for (int t = 0; t < 5; ++t) {
            const int r = gate*20 + (jA0 + t);
            float wf[8];
            #pragma unroll
            for (int i = 0; i < 8; ++i) {
                const int k = grp*8 + i;
                float v = 0.0f;
                if (k < 20)      v = Whh[r*20 + k];
                else if (k < 24) {
                    v = Wih[r*4 + (k - 20)];
                    if (k == 20 || k == 22) v *= LN2_OVER_P;
                }
                wf[i] = v * sg;
            }
            union { unsigned u[4]; bf16x8 v; } pk;
            #pragma unroll
            for (int q = 0; q < 4; ++q) {
                unsigned r_;
                asm("v_cvt_pk_bf16_f32 %0, %1, %2" : "=v"(r_) : "v"(wf[2*q]), "v"(wf[2*q+1]));
                pk.u[q] = r_;
            }
            af[t] = pk.v;

            const int jj = 5*grp + t;
            f32x4 b;
            #pragma unroll
            for (int m = 0; m < 4; ++m) {
                const float sm = (m == 2) ? TWOLOG2E : -LOG2E;
                b[m] = (bih[m*20 + jj] + bhh[m*20 + jj]) * sm;
            }
            bias4[t] = b;
            wtwv[t] = Wtw[jj];
            wgwv[t] = Wgw[jj];
        }
    }
    const float wt20 = Wtw[20], wt21 = Wtw[21], tb = Wtb[0];
    const float wg20 = Wgw[20], wg21 = Wgw[21], gb = Wgb[0];

    const int o0   = (grp == 0) ? 0 : (grp == 1) ? 8  : 16;
    const int o1   = (grp == 0) ? 4 : (grp == 1) ? 12 : 16;
    const int cOff = 5 * grp;
    const int waveBase = (blockIdx.x * WAVES + wid) * (16 * NP);

    auto compute = [&](int p, const InSet& S) {
        const int e = waveBase + p*16 + e16;
        // tail inputs: issue now, used ~150 instrs later
        const float th = th1[e];
        const float ff = f1[e];
        const float ii = i1[e];
        const float dl = dl1[e];

        const float g = S.g, lv = S.lv;
        const float ax = fabsf(g);
        const bool  cg = ax >= EPSP;
        const float u0 = cg ? lg2(ax) : NEG_PL2E;
        const float x1 = cg ? copysignf(1.0f, g) : g * EXPP;
        const float al = fabsf(lv);
        const bool  cl = al >= EPSP;
        const float u2 = cl ? lg2(al) : NEG_PL2E;
        const float x3 = cl ? copysignf(1.0f, lv) : lv * EXPP;

        const bool z = (grp == 3);
        const float fa0 = z ? 0.0f : S.hA.x, fa1 = z ? 0.0f : S.hA.y;
        const float fa2 = z ? 0.0f : S.hA.z, fa3 = z ? 0.0f : S.hA.w;
        float fb0, fb1, fb2, fb3;
        if (grp == 2)      { fb0 = u0;  fb1 = x1;  fb2 = u2;  fb3 = x3; }
        else if (z)        { fb0 = 0.f; fb1 = 0.f; fb2 = 0.f; fb3 = 0.f; }
        else               { fb0 = S.hB.x; fb1 = S.hB.y; fb2 = S.hB.z; fb3 = S.hB.w; }

        union { unsigned u[4]; bf16x8 v; } bp;
        {
            unsigned r0, r1, r2, r3;
            asm("v_cvt_pk_bf16_f32 %0, %1, %2" : "=v"(r0) : "v"(fa0), "v"(fa1));
            asm("v_cvt_pk_bf16_f32 %0, %1, %2" : "=v"(r1) : "v"(fa2), "v"(fa3));
            asm("v_cvt_pk_bf16_f32 %0, %1, %2" : "=v"(r2) : "v"(fb0), "v"(fb1));
            asm("v_cvt_pk_bf16_f32 %0, %1, %2" : "=v"(r3) : "v"(fb2), "v"(fb3));
            bp.u[0] = r0; bp.u[1] = r1; bp.u[2] = r2; bp.u[3] = r3;
        }
        const bf16x8 bfrag = bp.v;

        f32x4 acc[5];
        #pragma unroll
        for (int t = 0; t < 5; ++t)
            acc[t] = __builtin_amdgcn_mfma_f32_16x16x32_bf16(af[t], bfrag, bias4[t], 0, 0, 0);

        float fac = 0.0f, iac = 0.0f;
        #pragma unroll
        for (int t = 0; t < 5; ++t) {
            const float si = rcp_(1.0f + ex2(acc[t][0]));
            const float sf = rcp_(1.0f + ex2(acc[t][1]));
            const float tg = 1.0f - 2.0f * rcp_(1.0f + ex2(acc[t][2]));
            const float so = rcp_(1.0f + ex2(acc[t][3]));
            const float ct = sf * S.c5[t] + si * tg;
            const float ht = so * (1.0f - 2.0f * rcp_(1.0f + ex2(TWOLOG2E * ct)));
            fac += ht * wtwv[t];
            iac += ht * wgwv[t];
        }
        fac += __shfl_xor(fac, 16); fac += __shfl_xor(fac, 32);
        iac += __shfl_xor(iac, 16); iac += __shfl_xor(iac, 32);

        if (grp == 0) {
            const float ft = rcp_(1.0f + ex2(-LOG2E * (fac + tb + th*wt20 + ff*wt21)));
            const float it = rcp_(1.0f + ex2(-LOG2E * (iac + gb + th*wg20 + ii*wg21)));
            out[e] = ft*th + 0.1f*dl - it*g;
        }
    };

    // ---- software pipeline: double-buffered input sets, unroll-by-2 ----
    InSet A, B;
    load_set(grad, loss, h0, c0, waveBase + e16, o0, o1, cOff, A);
    #pragma unroll 1
    for (int p = 0; p < NP; p += 2) {
        load_set(grad, loss, h0, c0, waveBase + (p+1)*16 + e16, o0, o1, cOff, B);
        compute(p, A);
        const int pn = (p + 2 < NP) ? (p + 2) : (NP - 1);
        load_set(grad, loss, h0, c0, waveBase + pn*16 + e16, o0, o1, cOff, A);
        compute(p + 1, B);
    }
}

extern "C" void kernel_launch(void* const* d_in, const int* in_sizes, int n_in,
                              void* d_out, int out_size, void* d_ws, size_t ws_size,
                              hipStream_t stream) {
    const float* grad = (const float*)d_in[0];
    const float* loss = (const float*)d_in[1];
    const float* f1   = (const float*)d_in[2];
    const float* i1   = (const float*)d_in[3];
    const float* th1  = (const float*)d_in[4];
    const float* dl1  = (const float*)d_in[5];
    const float* h0   = (const float*)d_in[6];
    const float* c0   = (const float*)d_in[7];
    const float* Wih  = (const float*)d_in[8];
    const float* Whh  = (const float*)d_in[9];
    const float* bih  = (const float*)d_in[10];
    const float* bhh  = (const float*)d_in[11];
    const float* Wtw  = (const float*)d_in[12];
    const float* Wtb  = (const float*)d_in[13];
    const float* Wgw  = (const float*)d_in[14];
    const float* Wgb  = (const float*)d_in[15];

    const int N = in_sizes[0];                 // 4194304
    const int blocks = N / (16 * NP * WAVES);  // 4096
    hipLaunchKernelGGL(lstm_opt_mfma, dim3(blocks), dim3(BLK), 0, stream,
                       grad, loss, f1, i1, th1, dl1, h0, c0,
                       Wih, Whh, bih, bhh, Wtw, Wtb, Wgw, Wgb,
                       (float*)d_out);
}